// Round 1
// baseline (637.130 us; speedup 1.0000x reference)
//
#include <hip/hip_runtime.h>
#include <math.h>

#define Bb 4
#define Ss 2048
#define Dd 1024
#define Pp 9
#define DMm 256
#define Tt (Bb*Ss)
#define EPSf 1e-5f

#define BM 64
#define BN 64
#define BK 16

// ---------------------------------------------------------------- mix
__global__ __launch_bounds__(256) void k_mix(const float* __restrict__ x,
    const float* __restrict__ mk, float* __restrict__ xm) {
  const int t = blockIdx.x;          // token in [0, B*S)
  const int s = t & (Ss - 1);        // position within sequence
  const int d = threadIdx.x << 2;
  const float* xc = x + (size_t)t * Dd + d;
  float4 vb = *(const float4*)xc;
  float4 va = make_float4(0.f, 0.f, 0.f, 0.f);
  float4 vc = make_float4(0.f, 0.f, 0.f, 0.f);
  if (s > 0)      va = *(const float4*)(xc - Dd);
  if (s < Ss - 1) vc = *(const float4*)(xc + Dd);
  const float4 k0 = *(const float4*)(mk + d);
  const float4 k1 = *(const float4*)(mk + Dd + d);
  const float4 k2 = *(const float4*)(mk + 2 * Dd + d);
  float4 o;
  o.x = k0.x * va.x + k1.x * vb.x + k2.x * vc.x;
  o.y = k0.y * va.y + k1.y * vb.y + k2.y * vc.y;
  o.z = k0.z * va.z + k1.z * vb.z + k2.z * vc.z;
  o.w = k0.w * va.w + k1.w * vb.w + k2.w * vc.w;
  *(float4*)(xm + (size_t)t * Dd + d) = o;
}

// ---------------------------------------------------------------- observer hidden GEMM
// hidden[t, n] = tanh(sum_d xm[t,d] * Wo1[d,n] + bo1[n]);  [8192,1024]x[1024,256]
__global__ __launch_bounds__(256) void k_obs(const float* __restrict__ xm,
    const float* __restrict__ Wo1, const float* __restrict__ bo1,
    float* __restrict__ hidden) {
  __shared__ float As[BK][BM + 4];
  __shared__ float Bs[BK][BN + 4];
  const int row0 = blockIdx.x * BM;
  const int n0 = blockIdx.y * BN;
  const int tid = threadIdx.x;
  const int tx = tid & 15, ty = tid >> 4;
  float acc[4][4] = {};
  for (int kb = 0; kb < Dd; kb += BK) {
    #pragma unroll
    for (int l = tid; l < BM * BK; l += 256) {
      int i = l >> 4, kk = l & 15;
      As[kk][i] = xm[(size_t)(row0 + i) * Dd + kb + kk];
    }
    #pragma unroll
    for (int l = tid; l < BK * BN; l += 256) {
      int kk = l >> 6, j = l & 63;
      Bs[kk][j] = Wo1[(size_t)(kb + kk) * DMm + n0 + j];
    }
    __syncthreads();
    #pragma unroll
    for (int kk = 0; kk < BK; ++kk) {
      float a[4], b[4];
      #pragma unroll
      for (int i = 0; i < 4; ++i) a[i] = As[kk][ty * 4 + i];
      #pragma unroll
      for (int j = 0; j < 4; ++j) b[j] = Bs[kk][tx * 4 + j];
      #pragma unroll
      for (int i = 0; i < 4; ++i)
        #pragma unroll
        for (int j = 0; j < 4; ++j)
          acc[i][j] += a[i] * b[j];
    }
    __syncthreads();
  }
  #pragma unroll
  for (int i = 0; i < 4; ++i) {
    const int r = row0 + ty * 4 + i;
    #pragma unroll
    for (int j = 0; j < 4; ++j) {
      const int n = n0 + tx * 4 + j;
      hidden[(size_t)r * DMm + n] = tanhf(acc[i][j] + bo1[n]);
    }
  }
}

// ---------------------------------------------------------------- scores + argmax + near-tie flag
__global__ __launch_bounds__(256) void k_score(const float* __restrict__ hidden,
    const float* __restrict__ Wo2, const float* __restrict__ bo2,
    int* __restrict__ idx, int* __restrict__ nflag, int* __restrict__ flagged) {
  __shared__ float sW[DMm * Pp];
  const int tid = threadIdx.x;
  for (int l = tid; l < DMm * Pp; l += 256) sW[l] = Wo2[l];
  __syncthreads();
  const int wave = tid >> 6, lane = tid & 63;
  const int t = blockIdx.x * 4 + wave;
  const float4 h = *(const float4*)(hidden + (size_t)t * DMm + lane * 4);
  const int m = lane * 4;
  float part[Pp];
  #pragma unroll
  for (int pp = 0; pp < Pp; ++pp)
    part[pp] = h.x * sW[(m + 0) * Pp + pp] + h.y * sW[(m + 1) * Pp + pp]
             + h.z * sW[(m + 2) * Pp + pp] + h.w * sW[(m + 3) * Pp + pp];
  #pragma unroll
  for (int off = 32; off > 0; off >>= 1)
    #pragma unroll
    for (int pp = 0; pp < Pp; ++pp)
      part[pp] += __shfl_xor(part[pp], off);
  if (lane == 0) {
    float best = -1e30f, second = -1e30f;
    int bi = 0;
    #pragma unroll
    for (int pp = 0; pp < Pp; ++pp) {
      const float sc = part[pp] + bo2[pp];
      if (sc > best) { second = best; best = sc; bi = pp; }
      else if (sc > second) second = sc;
    }
    idx[t] = bi;
    if (best - second < 1e-3f) {
      const int pos = atomicAdd(nflag, 1);
      flagged[pos] = t;
    }
  }
}

// ---------------------------------------------------------------- fp64 rescue for near-ties
__global__ __launch_bounds__(256) void k_rescue(const float* __restrict__ xm,
    const float* __restrict__ Wo1, const float* __restrict__ bo1,
    const float* __restrict__ Wo2, const float* __restrict__ bo2,
    const int* __restrict__ nflag, const int* __restrict__ flagged,
    int* __restrict__ idx) {
  __shared__ float sx[Dd];
  __shared__ double th[DMm];
  __shared__ double sc[Pp];
  const int nf = *nflag;
  for (int f = blockIdx.x; f < nf; f += gridDim.x) {
    const int t = flagged[f];
    for (int l = threadIdx.x; l < Dd; l += 256) sx[l] = xm[(size_t)t * Dd + l];
    __syncthreads();
    const int m = threadIdx.x;
    double acc = (double)bo1[m];
    for (int d = 0; d < Dd; ++d)
      acc += (double)sx[d] * (double)Wo1[(size_t)d * DMm + m];
    th[m] = tanh(acc);
    __syncthreads();
    if (m < Pp) {
      double s = (double)bo2[m];
      for (int mm = 0; mm < DMm; ++mm) s += th[mm] * (double)Wo2[mm * Pp + m];
      sc[m] = s;
    }
    __syncthreads();
    if (threadIdx.x == 0) {
      double best = sc[0]; int bi = 0;
      for (int pp = 1; pp < Pp; ++pp) if (sc[pp] > best) { best = sc[pp]; bi = pp; }
      idx[t] = bi;
    }
    __syncthreads();
  }
}

// ---------------------------------------------------------------- group tokens by path
__global__ __launch_bounds__(256) void k_scatter(const int* __restrict__ idx,
    int* __restrict__ counts, int* __restrict__ tokenlist) {
  const int t = blockIdx.x * 256 + threadIdx.x;
  const int p = idx[t];
  const int pos = atomicAdd(&counts[p], 1);
  tokenlist[p * Tt + pos] = t;
}

// ---------------------------------------------------------------- grouped GEMM 1: h1 = xm @ W1[p] + b1[p]
__global__ __launch_bounds__(256) void k_h1(const float* __restrict__ xm,
    const float* __restrict__ W1, const float* __restrict__ b1,
    const int* __restrict__ counts, const int* __restrict__ tokenlist,
    float* __restrict__ h1) {
  const int p = blockIdx.z;
  const int cnt = counts[p];
  const int tile0 = blockIdx.x * BM;
  if (tile0 >= cnt) return;
  __shared__ int tl[BM];
  __shared__ float As[BK][BM + 4];
  __shared__ float Bs[BK][BN + 4];
  const int tid = threadIdx.x;
  if (tid < BM) {
    const int li = tile0 + tid;
    tl[tid] = (li < cnt) ? tokenlist[p * Tt + li] : -1;
  }
  __syncthreads();
  const float* W1p = W1 + (size_t)p * Dd * DMm;
  const int n0 = blockIdx.y * BN;
  const int tx = tid & 15, ty = tid >> 4;
  float acc[4][4] = {};
  for (int kb = 0; kb < Dd; kb += BK) {
    #pragma unroll
    for (int l = tid; l < BM * BK; l += 256) {
      int i = l >> 4, kk = l & 15;
      int t = tl[i];
      As[kk][i] = (t >= 0) ? xm[(size_t)t * Dd + kb + kk] : 0.f;
    }
    #pragma unroll
    for (int l = tid; l < BK * BN; l += 256) {
      int kk = l >> 6, j = l & 63;
      Bs[kk][j] = W1p[(size_t)(kb + kk) * DMm + n0 + j];
    }
    __syncthreads();
    #pragma unroll
    for (int kk = 0; kk < BK; ++kk) {
      float a[4], b[4];
      #pragma unroll
      for (int i = 0; i < 4; ++i) a[i] = As[kk][ty * 4 + i];
      #pragma unroll
      for (int j = 0; j < 4; ++j) b[j] = Bs[kk][tx * 4 + j];
      #pragma unroll
      for (int i = 0; i < 4; ++i)
        #pragma unroll
        for (int j = 0; j < 4; ++j)
          acc[i][j] += a[i] * b[j];
    }
    __syncthreads();
  }
  #pragma unroll
  for (int i = 0; i < 4; ++i) {
    const int t = tl[ty * 4 + i];
    if (t < 0) continue;
    #pragma unroll
    for (int j = 0; j < 4; ++j) {
      const int n = n0 + tx * 4 + j;
      h1[(size_t)t * DMm + n] = acc[i][j] + b1[p * DMm + n];
    }
  }
}

// ---------------------------------------------------------------- grouped GEMM 2: out = h1 @ W2[p] + b2[p] + x
__global__ __launch_bounds__(256) void k_out(const float* __restrict__ h1,
    const float* __restrict__ W2, const float* __restrict__ b2,
    const float* __restrict__ x, const int* __restrict__ counts,
    const int* __restrict__ tokenlist, float* __restrict__ out) {
  const int p = blockIdx.z;
  const int cnt = counts[p];
  const int tile0 = blockIdx.x * BM;
  if (tile0 >= cnt) return;
  __shared__ int tl[BM];
  __shared__ float As[BK][BM + 4];
  __shared__ float Bs[BK][BN + 4];
  const int tid = threadIdx.x;
  if (tid < BM) {
    const int li = tile0 + tid;
    tl[tid] = (li < cnt) ? tokenlist[p * Tt + li] : -1;
  }
  __syncthreads();
  const float* W2p = W2 + (size_t)p * DMm * Dd;
  const int n0 = blockIdx.y * BN;
  const int tx = tid & 15, ty = tid >> 4;
  float acc[4][4] = {};
  for (int kb = 0; kb < DMm; kb += BK) {
    #pragma unroll
    for (int l = tid; l < BM * BK; l += 256) {
      int i = l >> 4, kk = l & 15;
      int t = tl[i];
      As[kk][i] = (t >= 0) ? h1[(size_t)t * DMm + kb + kk] : 0.f;
    }
    #pragma unroll
    for (int l = tid; l < BK * BN; l += 256) {
      int kk = l >> 6, j = l & 63;
      Bs[kk][j] = W2p[(size_t)(kb + kk) * Dd + n0 + j];
    }
    __syncthreads();
    #pragma unroll
    for (int kk = 0; kk < BK; ++kk) {
      float a[4], b[4];
      #pragma unroll
      for (int i = 0; i < 4; ++i) a[i] = As[kk][ty * 4 + i];
      #pragma unroll
      for (int j = 0; j < 4; ++j) b[j] = Bs[kk][tx * 4 + j];
      #pragma unroll
      for (int i = 0; i < 4; ++i)
        #pragma unroll
        for (int j = 0; j < 4; ++j)
          acc[i][j] += a[i] * b[j];
    }
    __syncthreads();
  }
  #pragma unroll
  for (int i = 0; i < 4; ++i) {
    const int t = tl[ty * 4 + i];
    if (t < 0) continue;
    const int c0 = n0 + tx * 4;
    const float4 xv = *(const float4*)(x + (size_t)t * Dd + c0);
    const float4 bv = *(const float4*)(b2 + (size_t)p * Dd + c0);
    float4 o;
    o.x = acc[i][0] + bv.x + xv.x;
    o.y = acc[i][1] + bv.y + xv.y;
    o.z = acc[i][2] + bv.z + xv.z;
    o.w = acc[i][3] + bv.w + xv.w;
    *(float4*)(out + (size_t)t * Dd + c0) = o;
  }
}

// ---------------------------------------------------------------- in-place LayerNorm
__global__ __launch_bounds__(256) void k_ln(float* __restrict__ y,
    const float* __restrict__ gamma, const float* __restrict__ beta) {
  const int t = blockIdx.x;
  const int d = threadIdx.x << 2;
  float* row = y + (size_t)t * Dd;
  float4 v = *(float4*)(row + d);
  float s = v.x + v.y + v.z + v.w;
  float q = v.x * v.x + v.y * v.y + v.z * v.z + v.w * v.w;
  #pragma unroll
  for (int off = 32; off > 0; off >>= 1) {
    s += __shfl_xor(s, off);
    q += __shfl_xor(q, off);
  }
  __shared__ float ssum[4], sqq[4];
  const int wave = threadIdx.x >> 6, lane = threadIdx.x & 63;
  if (lane == 0) { ssum[wave] = s; sqq[wave] = q; }
  __syncthreads();
  s = ssum[0] + ssum[1] + ssum[2] + ssum[3];
  q = sqq[0] + sqq[1] + sqq[2] + sqq[3];
  const float mu = s * (1.f / Dd);
  const float var = q * (1.f / Dd) - mu * mu;
  const float inv = rsqrtf(var + EPSf);
  const float4 g = *(const float4*)(gamma + d);
  const float4 bt = *(const float4*)(beta + d);
  float4 o;
  o.x = (v.x - mu) * inv * g.x + bt.x;
  o.y = (v.y - mu) * inv * g.y + bt.y;
  o.z = (v.z - mu) * inv * g.z + bt.z;
  o.w = (v.w - mu) * inv * g.w + bt.w;
  *(float4*)(row + d) = o;
}

// ----------------------------------------------------------------
extern "C" void kernel_launch(void* const* d_in, const int* in_sizes, int n_in,
                              void* d_out, int out_size, void* d_ws, size_t ws_size,
                              hipStream_t stream) {
  (void)in_sizes; (void)n_in; (void)out_size; (void)ws_size;
  const float* x     = (const float*)d_in[0];
  const float* mk    = (const float*)d_in[1];
  const float* W1    = (const float*)d_in[2];
  const float* b1    = (const float*)d_in[3];
  const float* W2    = (const float*)d_in[4];
  const float* b2    = (const float*)d_in[5];
  const float* Wo1   = (const float*)d_in[6];
  const float* bo1   = (const float*)d_in[7];
  const float* Wo2   = (const float*)d_in[8];
  const float* bo2   = (const float*)d_in[9];
  const float* gamma = (const float*)d_in[10];
  const float* beta  = (const float*)d_in[11];
  float* out = (float*)d_out;

  // workspace layout
  float* xm     = (float*)d_ws;                     // Tt*Dd floats (33.6 MB)
  float* hidden = xm + (size_t)Tt * Dd;             // Tt*DMm floats (8.4 MB)
  float* h1     = hidden;                           // alias: hidden dead before h1 written
  int* idx      = (int*)(hidden + (size_t)Tt * DMm);
  int* counts   = idx + Tt;                         // 16 ints
  int* nflag    = counts + 16;                      // 1 int
  int* flagged  = counts + 32;                      // Tt ints
  int* tokenlist = flagged + Tt;                    // Pp*Tt ints

  hipMemsetAsync(counts, 0, 128, stream);           // counts + nflag

  k_mix<<<Tt, 256, 0, stream>>>(x, mk, xm);
  k_obs<<<dim3(Tt / BM, DMm / BN), 256, 0, stream>>>(xm, Wo1, bo1, hidden);
  k_score<<<Tt / 4, 256, 0, stream>>>(hidden, Wo2, bo2, idx, nflag, flagged);
  k_rescue<<<64, 256, 0, stream>>>(xm, Wo1, bo1, Wo2, bo2, nflag, flagged, idx);
  k_scatter<<<Tt / 256, 256, 0, stream>>>(idx, counts, tokenlist);
  k_h1<<<dim3(Tt / BM, DMm / BN, Pp), 256, 0, stream>>>(xm, W1, b1, counts, tokenlist, h1);
  k_out<<<dim3(Tt / BM, Dd / BN, Pp), 256, 0, stream>>>(h1, W2, b2, x, counts, tokenlist, out);
  k_ln<<<Tt, 256, 0, stream>>>(out, gamma, beta);
}

// Round 2
// 233.376 us; speedup vs baseline: 2.7301x; 2.7301x over previous
//
#include <hip/hip_runtime.h>
#include <math.h>

#define Ss 2048
#define Dd 1024
#define Pp 9
#define DMm 256
#define Tt 8192
#define EPSf 1e-5f
#define LSTR 40          // LDS row stride in bf16 elements (80B) -> 2-way (free) bank pattern
#define BAND 6e-3f       // fp64-rescue band for argmax ties (~8.5 sigma of bf16 score noise)

typedef __attribute__((ext_vector_type(8))) __bf16 bf16x8;
typedef __attribute__((ext_vector_type(4))) float f32x4;

__device__ __forceinline__ unsigned short bf16rn(float f) {
  unsigned int u = __float_as_uint(f);
  unsigned int r = (u + 0x7fffu + ((u >> 16) & 1u)) >> 16;
  return (unsigned short)r;
}

// ---------------------------------------------------------------- mix -> bf16
__global__ __launch_bounds__(256) void k_mix2(const float* __restrict__ x,
    const float* __restrict__ mk, unsigned short* __restrict__ xh) {
  const int t = blockIdx.x;
  const int s = t & (Ss - 1);
  const int d = threadIdx.x << 2;
  const float* xc = x + (size_t)t * Dd + d;
  float4 vb = *(const float4*)xc;
  float4 va = make_float4(0.f, 0.f, 0.f, 0.f);
  float4 vc = make_float4(0.f, 0.f, 0.f, 0.f);
  if (s > 0)      va = *(const float4*)(xc - Dd);
  if (s < Ss - 1) vc = *(const float4*)(xc + Dd);
  const float4 k0 = *(const float4*)(mk + d);
  const float4 k1 = *(const float4*)(mk + Dd + d);
  const float4 k2 = *(const float4*)(mk + 2 * Dd + d);
  float4 o;
  o.x = k0.x * va.x + k1.x * vb.x + k2.x * vc.x;
  o.y = k0.y * va.y + k1.y * vb.y + k2.y * vc.y;
  o.z = k0.z * va.z + k1.z * vb.z + k2.z * vc.z;
  o.w = k0.w * va.w + k1.w * vb.w + k2.w * vc.w;
  ushort4 h;
  h.x = bf16rn(o.x); h.y = bf16rn(o.y); h.z = bf16rn(o.z); h.w = bf16rn(o.w);
  *(ushort4*)(xh + (size_t)t * Dd + d) = h;
}

// ---------------------------------------------------------------- convert + transpose weights to bf16 [C][R]
__global__ __launch_bounds__(256) void k_cvtT(const float* __restrict__ in,
    unsigned short* __restrict__ out, int R, int C) {
  const size_t zo = (size_t)blockIdx.z * R * C;
  __shared__ float tile[32][33];
  const int r0 = blockIdx.x * 32, c0 = blockIdx.y * 32;
  const int tr = threadIdx.x >> 3, tc = (threadIdx.x & 7) << 2;
  float4 v = *(const float4*)(in + zo + (size_t)(r0 + tr) * C + c0 + tc);
  tile[tr][tc] = v.x; tile[tr][tc + 1] = v.y; tile[tr][tc + 2] = v.z; tile[tr][tc + 3] = v.w;
  __syncthreads();
  ushort4 h;
  h.x = bf16rn(tile[tc + 0][tr]); h.y = bf16rn(tile[tc + 1][tr]);
  h.z = bf16rn(tile[tc + 2][tr]); h.w = bf16rn(tile[tc + 3][tr]);
  *(ushort4*)(out + zo + (size_t)(c0 + tr) * R + r0 + tc) = h;
}

// ---------------------------------------------------------------- MFMA GEMM: C[64x64 tile] = gatherA[64,K] @ Bt[n][K]^T + bias
// MODE 0: outf = tanh(acc+bias) (dense, obs hidden)
// MODE 1: outh = bf16(acc+bias) (grouped, h1)
// MODE 2: outf = acc+bias+resid (grouped, out)
template<int KTOT, int NTOT, int MODE>
__global__ __launch_bounds__(256) void k_gemm(
    const unsigned short* __restrict__ A,
    const unsigned short* __restrict__ Bt,
    const float* __restrict__ bias,
    const float* __restrict__ resid,
    float* __restrict__ outf, unsigned short* __restrict__ outh,
    const int* __restrict__ counts, const int* __restrict__ tokenlist) {
  const int z = blockIdx.z;
  const int cnt = counts ? counts[z] : Tt;
  const int tile0 = blockIdx.x * 64;
  if (tile0 >= cnt) return;
  __shared__ int tl[64];
  __shared__ unsigned short As[64 * LSTR];
  __shared__ unsigned short Bs[64 * LSTR];
  const int tid = threadIdx.x;
  if (tid < 64) {
    const int li = tile0 + tid;
    tl[tid] = tokenlist ? ((li < cnt) ? tokenlist[z * Tt + li] : -1) : li;
  }
  __syncthreads();
  const int row = tid >> 2, slot = tid & 3;
  const int ta = tl[row];
  const unsigned short* Ap = (ta >= 0) ? (A + (size_t)ta * KTOT + slot * 8) : nullptr;
  const int n0 = blockIdx.y * 64;
  const unsigned short* Bp = Bt + (size_t)z * NTOT * KTOT + (size_t)(n0 + row) * KTOT + slot * 8;
  const int lane = tid & 63, wv = tid >> 6;
  const int wr = wv >> 1, wc = wv & 1;
  const int fr = lane & 15, fs = lane >> 4;
  const int aoff = (wr * 32 + fr) * LSTR + fs * 8;
  const int boff = (wc * 32 + fr) * LSTR + fs * 8;
  const int wbase = row * LSTR + slot * 8;
  f32x4 acc[2][2] = {};
  for (int kb = 0; kb < KTOT; kb += 32) {
    const float4 av = Ap ? *(const float4*)(Ap + kb) : make_float4(0.f, 0.f, 0.f, 0.f);
    const float4 bv = *(const float4*)(Bp + kb);
    *(float4*)&As[wbase] = av;
    *(float4*)&Bs[wbase] = bv;
    __syncthreads();
    const bf16x8 a0 = *(const bf16x8*)&As[aoff];
    const bf16x8 a1 = *(const bf16x8*)&As[aoff + 16 * LSTR];
    const bf16x8 b0 = *(const bf16x8*)&Bs[boff];
    const bf16x8 b1 = *(const bf16x8*)&Bs[boff + 16 * LSTR];
    acc[0][0] = __builtin_amdgcn_mfma_f32_16x16x32_bf16(a0, b0, acc[0][0], 0, 0, 0);
    acc[0][1] = __builtin_amdgcn_mfma_f32_16x16x32_bf16(a0, b1, acc[0][1], 0, 0, 0);
    acc[1][0] = __builtin_amdgcn_mfma_f32_16x16x32_bf16(a1, b0, acc[1][0], 0, 0, 0);
    acc[1][1] = __builtin_amdgcn_mfma_f32_16x16x32_bf16(a1, b1, acc[1][1], 0, 0, 0);
    __syncthreads();
  }
  // C/D layout (m89-verified): col = lane&15, row = (lane>>4)*4 + j
  #pragma unroll
  for (int m = 0; m < 2; ++m) {
    #pragma unroll
    for (int j = 0; j < 4; ++j) {
      const int r = wr * 32 + m * 16 + fs * 4 + j;
      const int t = tl[r];
      if (t < 0) continue;
      #pragma unroll
      for (int n = 0; n < 2; ++n) {
        const int c = n0 + wc * 32 + n * 16 + fr;
        const float v = acc[m][n][j] + bias[(size_t)z * NTOT + c];
        if (MODE == 0)      outf[(size_t)t * NTOT + c] = tanhf(v);
        else if (MODE == 1) outh[(size_t)t * NTOT + c] = bf16rn(v);
        else                outf[(size_t)t * NTOT + c] = v + resid[(size_t)t * NTOT + c];
      }
    }
  }
}

// ---------------------------------------------------------------- scores + argmax + near-tie flag
__global__ __launch_bounds__(256) void k_score(const float* __restrict__ hidden,
    const float* __restrict__ Wo2, const float* __restrict__ bo2,
    int* __restrict__ idx, int* __restrict__ nflag, int* __restrict__ flagged) {
  __shared__ float sW[DMm * Pp];
  const int tid = threadIdx.x;
  for (int l = tid; l < DMm * Pp; l += 256) sW[l] = Wo2[l];
  __syncthreads();
  const int wave = tid >> 6, lane = tid & 63;
  const int t = blockIdx.x * 4 + wave;
  const float4 h = *(const float4*)(hidden + (size_t)t * DMm + lane * 4);
  const int m = lane * 4;
  float part[Pp];
  #pragma unroll
  for (int pp = 0; pp < Pp; ++pp)
    part[pp] = h.x * sW[(m + 0) * Pp + pp] + h.y * sW[(m + 1) * Pp + pp]
             + h.z * sW[(m + 2) * Pp + pp] + h.w * sW[(m + 3) * Pp + pp];
  #pragma unroll
  for (int off = 32; off > 0; off >>= 1)
    #pragma unroll
    for (int pp = 0; pp < Pp; ++pp)
      part[pp] += __shfl_xor(part[pp], off);
  if (lane == 0) {
    float best = -1e30f, second = -1e30f;
    int bi = 0;
    #pragma unroll
    for (int pp = 0; pp < Pp; ++pp) {
      const float sc = part[pp] + bo2[pp];
      if (sc > best) { second = best; best = sc; bi = pp; }
      else if (sc > second) second = sc;
    }
    idx[t] = bi;
    if (best - second < BAND) {
      const int pos = atomicAdd(nflag, 1);
      flagged[pos] = t;
    }
  }
}

// ---------------------------------------------------------------- fp64 rescue for near-ties (recomputes mix exactly)
__global__ __launch_bounds__(256) void k_rescue(const float* __restrict__ x,
    const float* __restrict__ mk,
    const float* __restrict__ Wo1, const float* __restrict__ bo1,
    const float* __restrict__ Wo2, const float* __restrict__ bo2,
    const int* __restrict__ nflag, const int* __restrict__ flagged,
    int* __restrict__ idx) {
  __shared__ double sx[Dd];
  __shared__ double th[DMm];
  __shared__ double sc[Pp];
  const int nf = *nflag;
  for (int f = blockIdx.x; f < nf; f += gridDim.x) {
    const int t = flagged[f];
    const int s = t & (Ss - 1);
    for (int l = threadIdx.x; l < Dd; l += 256) {
      const double xa = (s > 0)      ? (double)x[(size_t)(t - 1) * Dd + l] : 0.0;
      const double xb =                (double)x[(size_t)t * Dd + l];
      const double xc = (s < Ss - 1) ? (double)x[(size_t)(t + 1) * Dd + l] : 0.0;
      sx[l] = (double)mk[l] * xa + (double)mk[Dd + l] * xb + (double)mk[2 * Dd + l] * xc;
    }
    __syncthreads();
    const int m = threadIdx.x;
    double acc = (double)bo1[m];
    for (int d = 0; d < Dd; ++d)
      acc += sx[d] * (double)Wo1[(size_t)d * DMm + m];
    th[m] = tanh(acc);
    __syncthreads();
    if (m < Pp) {
      double sv = (double)bo2[m];
      for (int mm = 0; mm < DMm; ++mm) sv += th[mm] * (double)Wo2[mm * Pp + m];
      sc[m] = sv;
    }
    __syncthreads();
    if (m == 0) {
      double best = sc[0]; int bi = 0;
      for (int pp = 1; pp < Pp; ++pp) if (sc[pp] > best) { best = sc[pp]; bi = pp; }
      idx[t] = bi;
    }
    __syncthreads();
  }
}

// ---------------------------------------------------------------- group tokens by path
__global__ __launch_bounds__(256) void k_scatter(const int* __restrict__ idx,
    int* __restrict__ counts, int* __restrict__ tokenlist) {
  const int t = blockIdx.x * 256 + threadIdx.x;
  const int p = idx[t];
  const int pos = atomicAdd(&counts[p], 1);
  tokenlist[p * Tt + pos] = t;
}

// ---------------------------------------------------------------- in-place LayerNorm
__global__ __launch_bounds__(256) void k_ln(float* __restrict__ y,
    const float* __restrict__ gamma, const float* __restrict__ beta) {
  const int t = blockIdx.x;
  const int d = threadIdx.x << 2;
  float* row = y + (size_t)t * Dd;
  float4 v = *(float4*)(row + d);
  float s = v.x + v.y + v.z + v.w;
  float q = v.x * v.x + v.y * v.y + v.z * v.z + v.w * v.w;
  #pragma unroll
  for (int off = 32; off > 0; off >>= 1) {
    s += __shfl_xor(s, off);
    q += __shfl_xor(q, off);
  }
  __shared__ float ssum[4], sqq[4];
  const int wave = threadIdx.x >> 6, lane = threadIdx.x & 63;
  if (lane == 0) { ssum[wave] = s; sqq[wave] = q; }
  __syncthreads();
  s = ssum[0] + ssum[1] + ssum[2] + ssum[3];
  q = sqq[0] + sqq[1] + sqq[2] + sqq[3];
  const float mu = s * (1.f / Dd);
  const float var = q * (1.f / Dd) - mu * mu;
  const float inv = rsqrtf(var + EPSf);
  const float4 g = *(const float4*)(gamma + d);
  const float4 bt = *(const float4*)(beta + d);
  float4 o;
  o.x = (v.x - mu) * inv * g.x + bt.x;
  o.y = (v.y - mu) * inv * g.y + bt.y;
  o.z = (v.z - mu) * inv * g.z + bt.z;
  o.w = (v.w - mu) * inv * g.w + bt.w;
  *(float4*)(row + d) = o;
}

// ----------------------------------------------------------------
extern "C" void kernel_launch(void* const* d_in, const int* in_sizes, int n_in,
                              void* d_out, int out_size, void* d_ws, size_t ws_size,
                              hipStream_t stream) {
  (void)in_sizes; (void)n_in; (void)out_size; (void)ws_size;
  const float* x     = (const float*)d_in[0];
  const float* mk    = (const float*)d_in[1];
  const float* W1    = (const float*)d_in[2];
  const float* b1    = (const float*)d_in[3];
  const float* W2    = (const float*)d_in[4];
  const float* b2    = (const float*)d_in[5];
  const float* Wo1   = (const float*)d_in[6];
  const float* bo1   = (const float*)d_in[7];
  const float* Wo2   = (const float*)d_in[8];
  const float* bo2   = (const float*)d_in[9];
  const float* gamma = (const float*)d_in[10];
  const float* beta  = (const float*)d_in[11];
  float* out = (float*)d_out;

  // workspace layout (~35.5 MB)
  size_t off = 0;
  auto alloc = [&](size_t bytes) -> void* {
    void* p = (char*)d_ws + off;
    off += (bytes + 255) & ~(size_t)255;
    return p;
  };
  unsigned short* xm_h  = (unsigned short*)alloc((size_t)Tt * Dd * 2);
  float*          hidden = (float*)alloc((size_t)Tt * DMm * 4);
  unsigned short* h1    = (unsigned short*)hidden;  // alias: hidden dead before h1 written
  unsigned short* W1t   = (unsigned short*)alloc((size_t)Pp * Dd * DMm * 2);
  unsigned short* W2t   = (unsigned short*)alloc((size_t)Pp * DMm * Dd * 2);
  unsigned short* Wo1t  = (unsigned short*)alloc((size_t)Dd * DMm * 2);
  int* idx      = (int*)alloc(Tt * 4);
  int* counts   = (int*)alloc(64 * 4);
  int* nflag    = counts + 16;
  int* flagged  = (int*)alloc(Tt * 4);
  int* tokenlist = (int*)alloc((size_t)Pp * Tt * 4);

  hipMemsetAsync(counts, 0, 256, stream);

  k_mix2<<<Tt, 256, 0, stream>>>(x, mk, xm_h);
  k_cvtT<<<dim3(Dd / 32, DMm / 32, Pp), 256, 0, stream>>>(W1, W1t, Dd, DMm);
  k_cvtT<<<dim3(DMm / 32, Dd / 32, Pp), 256, 0, stream>>>(W2, W2t, DMm, Dd);
  k_cvtT<<<dim3(Dd / 32, DMm / 32, 1), 256, 0, stream>>>(Wo1, Wo1t, Dd, DMm);

  k_gemm<Dd, DMm, 0><<<dim3(Tt / 64, DMm / 64, 1), 256, 0, stream>>>(
      xm_h, Wo1t, bo1, nullptr, hidden, nullptr, nullptr, nullptr);
  k_score<<<Tt / 4, 256, 0, stream>>>(hidden, Wo2, bo2, idx, nflag, flagged);
  k_rescue<<<256, 256, 0, stream>>>(x, mk, Wo1, bo1, Wo2, bo2, nflag, flagged, idx);
  k_scatter<<<Tt / 256, 256, 0, stream>>>(idx, counts, tokenlist);

  k_gemm<Dd, DMm, 1><<<dim3(Tt / 64, DMm / 64, Pp), 256, 0, stream>>>(
      xm_h, W1t, b1, nullptr, nullptr, h1, counts, tokenlist);
  k_gemm<DMm, Dd, 2><<<dim3(Tt / 64, Dd / 64, Pp), 256, 0, stream>>>(
      h1, W2t, b2, x, out, nullptr, counts, tokenlist);
  k_ln<<<Tt, 256, 0, stream>>>(out, gamma, beta);
}